// Round 1
// baseline (819.459 us; speedup 1.0000x reference)
//
#include <hip/hip_runtime.h>
#include <math.h>

#define BB 1024
#define TT 25
#define LP 10
#define MAXD 11
#define LPAD 35   // T + LP
#define RS 36     // padded LDS row stride in floats (16B-aligned rows)

// ---------------------------------------------------------------------------
// Dense DCLS kernel generation, transposed layout: Kt[(i*MAXD + j)*O + o]
// Kt[o,i,j] = W[o,i] * X[j] / (sum_j X[j] + 1e-7),
// X[j] = exp(-0.5*((j - (P+5))/ (|SIG|+0.27))^2)
// ---------------------------------------------------------------------------
__global__ void gen_kernel(const float* __restrict__ W,
                           const float* __restrict__ P,
                           const float* __restrict__ SIG,
                           float* __restrict__ Kt, int O, int I) {
    int idx = blockIdx.x * blockDim.x + threadIdx.x;
    if (idx >= O * I) return;
    int i = idx % I;
    int o = idx / I;
    float w  = W[idx];
    float pc = P[idx] + (float)(MAXD / 2);
    float s  = fabsf(SIG[idx]) + 0.27f;
    float x[MAXD];
    float sum = 0.f;
#pragma unroll
    for (int j = 0; j < MAXD; ++j) {
        float d = ((float)j - pc) / s;
        x[j] = expf(-0.5f * d * d);
        sum += x[j];
    }
    float denom = sum + 1e-7f;
#pragma unroll
    for (int j = 0; j < MAXD; ++j) {
        Kt[(i * MAXD + j) * O + o] = w * (x[j] / denom);
    }
}

// ---------------------------------------------------------------------------
// Fused: DCLS conv (VALID, pre-generated dense kernel) + bias + eval-BN + LIF
// One block per batch element, 256 threads = 256 output channels.
// xin layout: (B, T, I). spk_out layout: (B, T, 256).
// ---------------------------------------------------------------------------
template <int I>
__global__ __launch_bounds__(256)
void conv_bn_lif_kernel(const float* __restrict__ xin,
                        const float* __restrict__ Kt,
                        const float* __restrict__ bias,
                        const float* __restrict__ gamma,
                        const float* __restrict__ beta,
                        const float* __restrict__ mean,
                        const float* __restrict__ var,
                        float* __restrict__ spk_out) {
    __shared__ __align__(16) float xs[I * RS];
    const int b   = blockIdx.x;
    const int tid = threadIdx.x;

    // zero full LDS tile (covers left pad + tail slot)
    for (int k = tid; k < I * RS; k += 256) xs[k] = 0.f;
    __syncthreads();
    // fill: xs[i][LP + t] = xin[b, t, i]   (coalesced global read)
    for (int k = tid; k < TT * I; k += 256) {
        int t = k / I;
        int i = k - t * I;
        xs[i * RS + LP + t] = xin[b * TT * I + k];
    }
    __syncthreads();

    const int o = tid;
    float y[TT];
#pragma unroll
    for (int t = 0; t < TT; ++t) y[t] = 0.f;

    for (int i = 0; i < I; ++i) {
        // LDS row -> registers via b128 reads (row is 16B aligned, RS=36)
        float xr[RS];
        const float4* xp = reinterpret_cast<const float4*>(&xs[i * RS]);
#pragma unroll
        for (int q = 0; q < RS / 4; ++q) {
            float4 v = xp[q];
            xr[4 * q + 0] = v.x; xr[4 * q + 1] = v.y;
            xr[4 * q + 2] = v.z; xr[4 * q + 3] = v.w;
        }
        // kernel taps, coalesced (lane = o)
        float kv[MAXD];
        const float* kp = &Kt[i * MAXD * 256 + o];
#pragma unroll
        for (int j = 0; j < MAXD; ++j) kv[j] = kp[j * 256];
        // 275 FMAs, all-register
#pragma unroll
        for (int j = 0; j < MAXD; ++j) {
            float kj = kv[j];
#pragma unroll
            for (int t = 0; t < TT; ++t) y[t] = fmaf(kj, xr[t + j], y[t]);
        }
    }

    // fold bias + BN:  a = y*scale + ofs
    float scale = gamma[o] / sqrtf(var[o] + 1e-5f);
    float ofs   = (bias[o] - mean[o]) * scale + beta[o];

    // LIF, reset-by-subtract, detached reset uses pre-update mem
    float memv = 0.f;
#pragma unroll
    for (int t = 0; t < TT; ++t) {
        float a     = y[t] * scale + ofs;
        float reset = (memv > 1.0f) ? 1.0f : 0.f;
        memv        = 0.95f * memv + a - reset;
        float spk   = (memv > 1.0f) ? 1.0f : 0.f;
        spk_out[(b * TT + t) * 256 + o] = spk;
    }
}

// ---------------------------------------------------------------------------
// Layer 3: DCLS conv (256 -> 20) + bias + LIF; writes spk3 and mem3 (T,B,20).
// One block per batch element; 8-way split of the input-channel reduction.
// ---------------------------------------------------------------------------
__global__ __launch_bounds__(256)
void layer3_kernel(const float* __restrict__ spk2,   // (B, T, 256)
                   const float* __restrict__ K3t,    // [(i*11 + j)*20 + o]
                   const float* __restrict__ b3,
                   float* __restrict__ out) {        // spk3 ++ mem3
    __shared__ __align__(16) float xs[256 * RS];
    __shared__ float ps[8 * 20 * TT];
    const int b   = blockIdx.x;
    const int tid = threadIdx.x;

    for (int k = tid; k < 256 * RS; k += 256) xs[k] = 0.f;
    __syncthreads();
    for (int k = tid; k < TT * 256; k += 256) {
        int t = k >> 8;
        int i = k & 255;
        xs[i * RS + LP + t] = spk2[b * TT * 256 + k];
    }
    __syncthreads();

    const int oslot  = tid & 31;   // 0..31 (20 active)
    const int ichunk = tid >> 5;   // 0..7, each covers 32 input channels

    if (oslot < 20) {
        float y[TT];
#pragma unroll
        for (int t = 0; t < TT; ++t) y[t] = 0.f;
        for (int ii = 0; ii < 32; ++ii) {
            int i = ichunk * 32 + ii;
            float xr[RS];
            const float4* xp = reinterpret_cast<const float4*>(&xs[i * RS]);
#pragma unroll
            for (int q = 0; q < RS / 4; ++q) {
                float4 v = xp[q];
                xr[4 * q + 0] = v.x; xr[4 * q + 1] = v.y;
                xr[4 * q + 2] = v.z; xr[4 * q + 3] = v.w;
            }
            float kv[MAXD];
            const float* kp = &K3t[i * MAXD * 20 + oslot];
#pragma unroll
            for (int j = 0; j < MAXD; ++j) kv[j] = kp[j * 20];
#pragma unroll
            for (int j = 0; j < MAXD; ++j) {
                float kj = kv[j];
#pragma unroll
                for (int t = 0; t < TT; ++t) y[t] = fmaf(kj, xr[t + j], y[t]);
            }
        }
#pragma unroll
        for (int t = 0; t < TT; ++t)
            ps[(ichunk * 20 + oslot) * TT + t] = y[t];
    }
    __syncthreads();

    if (tid < 20) {
        const int o = tid;
        float memv = 0.f;
        float bo   = b3[o];
#pragma unroll
        for (int t = 0; t < TT; ++t) {
            float a = bo;
#pragma unroll
            for (int c = 0; c < 8; ++c) a += ps[(c * 20 + o) * TT + t];
            float reset = (memv > 1.0f) ? 1.0f : 0.f;
            memv        = 0.95f * memv + a - reset;
            float spk   = (memv > 1.0f) ? 1.0f : 0.f;
            out[(t * BB + b) * 20 + o] = spk;                    // spk3
            out[TT * BB * 20 + (t * BB + b) * 20 + o] = memv;    // mem3
        }
    }
}

// ---------------------------------------------------------------------------
extern "C" void kernel_launch(void* const* d_in, const int* in_sizes, int n_in,
                              void* d_out, int out_size, void* d_ws, size_t ws_size,
                              hipStream_t stream) {
    const float* data = (const float*)d_in[0];
    const float* W1   = (const float*)d_in[1];
    const float* b1   = (const float*)d_in[2];
    const float* P1   = (const float*)d_in[3];
    const float* SIG1 = (const float*)d_in[4];
    const float* g1   = (const float*)d_in[5];
    const float* be1  = (const float*)d_in[6];
    const float* m1   = (const float*)d_in[7];
    const float* v1   = (const float*)d_in[8];
    const float* W2   = (const float*)d_in[9];
    const float* b2   = (const float*)d_in[10];
    const float* P2   = (const float*)d_in[11];
    const float* SIG2 = (const float*)d_in[12];
    const float* g2   = (const float*)d_in[13];
    const float* be2  = (const float*)d_in[14];
    const float* m2   = (const float*)d_in[15];
    const float* v2   = (const float*)d_in[16];
    const float* W3   = (const float*)d_in[17];
    const float* b3   = (const float*)d_in[18];
    const float* P3   = (const float*)d_in[19];
    const float* SIG3 = (const float*)d_in[20];
    float* out = (float*)d_out;

    // workspace layout (floats)
    float* ws   = (float*)d_ws;
    float* K1t  = ws;                          // 140*11*256 = 394240
    float* K2t  = K1t + 140 * MAXD * 256;      // 256*11*256 = 720896
    float* K3t  = K2t + 256 * MAXD * 256;      // 256*11*20  = 56320
    float* spk1 = K3t + 256 * MAXD * 20;       // 1024*25*256
    float* spk2 = spk1 + BB * TT * 256;        // 1024*25*256

    gen_kernel<<<(256 * 140 + 255) / 256, 256, 0, stream>>>(W1, P1, SIG1, K1t, 256, 140);
    gen_kernel<<<(256 * 256 + 255) / 256, 256, 0, stream>>>(W2, P2, SIG2, K2t, 256, 256);
    gen_kernel<<<(20 * 256 + 255) / 256, 256, 0, stream>>>(W3, P3, SIG3, K3t, 20, 256);

    conv_bn_lif_kernel<140><<<BB, 256, 0, stream>>>(data, K1t, b1, g1, be1, m1, v1, spk1);
    conv_bn_lif_kernel<256><<<BB, 256, 0, stream>>>(spk1, K2t, b2, g2, be2, m2, v2, spk2);
    layer3_kernel<<<BB, 256, 0, stream>>>(spk2, K3t, b3, out);
}